// Round 3
// baseline (133.105 us; speedup 1.0000x reference)
//
#include <hip/hip_runtime.h>
#include <stdint.h>

#define IN_F   4096
#define OUT_F  768
#define NB     8
#define BATCH  4096
#define WCOLS  (OUT_F*NB)   // 6144

typedef short  bf16x8  __attribute__((ext_vector_type(8)));
typedef float  f32x4   __attribute__((ext_vector_type(4)));
typedef unsigned short ushort8 __attribute__((ext_vector_type(8)));

__device__ __forceinline__ unsigned short f2bf(float f){
    union { float f; uint32_t u; } v; v.f = f;
    uint32_t u = v.u;
    u += 0x7FFFu + ((u >> 16) & 1u);   // round-to-nearest-even
    return (unsigned short)(u >> 16);
}

__device__ __forceinline__ float bf2f(unsigned short u){
    union { uint32_t q; float f; } v; v.q = ((uint32_t)u) << 16;
    return v.f;
}

__device__ __forceinline__ void gload16(const void* g, void* l){
    __builtin_amdgcn_global_load_lds(
        (const __attribute__((address_space(1))) unsigned int*)g,
        (__attribute__((address_space(3))) unsigned int*)l, 16, 0, 0);
}

// counted vmcnt wait + scheduler fence (rule #18)
#define WAITV(n) do {                                                   \
    asm volatile("s_waitcnt vmcnt(" #n ")" ::: "memory");               \
    __builtin_amdgcn_sched_barrier(0);                                  \
} while (0)

// ---------------- kernel 1: latent f32 -> bf16 ; zero accumulators ----------
__global__ void prep_latent(const float* __restrict__ lat,
                            unsigned short* __restrict__ abf,
                            float* __restrict__ acc){
    if (blockIdx.x == 0 && threadIdx.x < 4) acc[threadIdx.x] = 0.f;
    int idx = (blockIdx.x * 256 + threadIdx.x) * 8;   // 8 floats / thread
    const float4* p = (const float4*)(lat + idx);
    float4 a = p[0], b = p[1];
    ushort8 o;
    o[0]=f2bf(a.x); o[1]=f2bf(a.y); o[2]=f2bf(a.z); o[3]=f2bf(a.w);
    o[4]=f2bf(b.x); o[5]=f2bf(b.y); o[6]=f2bf(b.z); o[7]=f2bf(b.w);
    *(ushort8*)(abf + idx) = o;
}

// ---------------- kernel 2: sigmoid-decode weight -> int_weights^T (bf16) ---
__global__ void decode_weight(const float* __restrict__ w,
                              unsigned short* __restrict__ bt,
                              float* __restrict__ acc){
    __shared__ unsigned short tile[64][70];   // [n][k], padded stride
    __shared__ float part[4];
    const int tid = threadIdx.x;
    const int k0 = blockIdx.x * 64;
    const int n0 = blockIdx.y * 64;
    const int j     = tid & 63;        // n within tile
    const int ibase = (tid >> 6) * 16; // k within tile
    float pol = 0.f;
    #pragma unroll 4
    for (int r = 0; r < 16; ++r){
        int i = ibase + r;
        const float4* src = (const float4*)(w + (size_t)(k0+i)*WCOLS + (size_t)(n0+j)*8);
        float4 a = src[0], b = src[1];
        float x[8] = {a.x,a.y,a.z,a.w,b.x,b.y,b.z,b.w};
        float p[8];
        #pragma unroll
        for (int q = 0; q < 8; ++q){
            p[q] = 1.f / (1.f + __expf(-x[q]));
            pol += p[q] * (1.f - p[q]);
        }
        float iw = p[0] + 2.f*p[1] + 4.f*p[2] + 8.f*p[3]
                 + 16.f*p[4] + 32.f*p[5] + 64.f*p[6] - 128.f*p[7];
        tile[j][i] = f2bf(iw);
    }
    #pragma unroll
    for (int off = 32; off; off >>= 1) pol += __shfl_down(pol, off);
    if ((tid & 63) == 0) part[tid >> 6] = pol;
    __syncthreads();
    const int nrow = tid >> 4;
    const int kb   = (tid & 15) * 4;
    #pragma unroll
    for (int q = 0; q < 4; ++q){
        int n = nrow + q*16;
        uint2 v;
        v.x = *(const unsigned int*)&tile[n][kb];
        v.y = *(const unsigned int*)&tile[n][kb+2];
        *(uint2*)(bt + (size_t)(n0+n)*IN_F + k0 + kb) = v;
    }
    if (tid == 0) atomicAdd(&acc[1], part[0]+part[1]+part[2]+part[3]);
}

// ---------------- kernel 2b: true_sum bits -> isum (bf16, [BATCH][OUT_F]) ---
__global__ void ts_decode(const float* __restrict__ ts,
                          unsigned short* __restrict__ isum){
    const int tid = threadIdx.x;
    #pragma unroll
    for (int k = 0; k < 6; ++k){
        int e = blockIdx.x * 1536 + k * 256 + tid;
        const float4* q = (const float4*)(ts + (size_t)e * 8);
        float4 x = q[0], y = q[1];
        float v = x.x + 2.f*x.y + 4.f*x.z + 8.f*x.w
                + 16.f*y.x + 32.f*y.y + 64.f*y.z - 128.f*y.w;
        isum[e] = f2bf(v);
    }
}

// ---------------- kernel 3: bf16 GEMM, counted-vmcnt pipeline + fused loss --
#define BM 128
#define BN 96
#define BK 64
#define NT (IN_F/BK)            // 64 K-steps
#define ABYTES (BM*BK*2)        // 16384
#define BBYTES (BN*BK*2)        // 12288
#define BUFB   (ABYTES+BBYTES)  // 28672

__launch_bounds__(256)
__global__ void gemm_loss(const unsigned short* __restrict__ abf,
                          const unsigned short* __restrict__ bt,
                          const unsigned short* __restrict__ isum,
                          float* __restrict__ acc){
    __shared__ char smem[4*BUFB];   // 112 KB, 4 rotating buffers
    __shared__ float part[4];
    const int tid = threadIdx.x;
    const int w   = tid >> 6;
    const int l   = tid & 63;
    const int s   = l & 15, g = l >> 4;
    const int wr  = w >> 1, wc = w & 1;    // 2x2 waves, wave tile 64x48
    const int m0  = blockIdx.x * BM;
    const int n0  = blockIdx.y * BN;

    f32x4 accv[4][3];
    #pragma unroll
    for (int m = 0; m < 4; ++m)
        #pragma unroll
        for (int n = 0; n < 3; ++n)
            accv[m][n] = (f32x4){0.f,0.f,0.f,0.f};

    // staging: thread t covers rows r0+32i, chunk col t&7 (linear LDS dest);
    // source chunk col XOR-swizzled so swizzled ds_reads see logical k
    const int c8  = tid & 7;
    const int r0  = tid >> 3;                    // 0..31
    const int scw = ((c8 ^ (r0 & 7)) << 3);      // source element offset
    const unsigned short* aS = abf + (size_t)(m0 + r0) * IN_F + scw;
    const unsigned short* bS = bt  + (size_t)(n0 + r0) * IN_F + scw;

    #define STAGE(kt, base) do {                                           \
        const int _ko = (kt) * BK;                                         \
        char* _ad = (base) + tid*16;                                       \
        char* _bd = (base) + ABYTES + tid*16;                              \
        _Pragma("unroll")                                                  \
        for (int _i = 0; _i < 4; ++_i)                                     \
            gload16(aS + (size_t)_i*32*IN_F + _ko, _ad + _i*4096);         \
        _Pragma("unroll")                                                  \
        for (int _i = 0; _i < 3; ++_i)                                     \
            gload16(bS + (size_t)_i*32*IN_F + _ko, _bd + _i*4096);         \
    } while (0)

    #define COMPUTE(base) do {                                             \
        char* _Ab = (base);                                                \
        char* _Bb = (base) + ABYTES;                                       \
        _Pragma("unroll")                                                  \
        for (int _kk = 0; _kk < 2; ++_kk){                                 \
            bf16x8 _af[4], _bf[3];                                         \
            _Pragma("unroll")                                              \
            for (int _m = 0; _m < 4; ++_m){                                \
                int _r  = wr*64 + _m*16 + s;                               \
                int _ch = _r*8 + ((_kk*4 + g) ^ (_r & 7));                 \
                _af[_m] = *(const bf16x8*)(_Ab + _ch*16);                  \
            }                                                              \
            _Pragma("unroll")                                              \
            for (int _n = 0; _n < 3; ++_n){                                \
                int _r  = wc*48 + _n*16 + s;                               \
                int _ch = _r*8 + ((_kk*4 + g) ^ (_r & 7));                 \
                _bf[_n] = *(const bf16x8*)(_Bb + _ch*16);                  \
            }                                                              \
            _Pragma("unroll")                                              \
            for (int _m = 0; _m < 4; ++_m)                                 \
                _Pragma("unroll")                                          \
                for (int _n = 0; _n < 3; ++_n)                             \
                    accv[_m][_n] = __builtin_amdgcn_mfma_f32_16x16x32_bf16(\
                        _af[_m], _bf[_n], accv[_m][_n], 0, 0, 0);          \
        }                                                                  \
    } while (0)

    char* b0 = smem;
    char* b1 = smem + BUFB;
    char* b2 = smem + 2*BUFB;
    char* b3 = smem + 3*BUFB;

    // 3-deep prefetch; 21 loads/wave in flight; vmcnt never drained in loop.
    STAGE(0, b0);
    STAGE(1, b1);
    STAGE(2, b2);
    for (int t = 0; t < NT-3; ++t){
        WAITV(14);                         // oldest tile (t) landed in LDS
        __builtin_amdgcn_s_barrier();      // all waves' tile-t writes visible
        STAGE(t+3, b3);                    // b3 last read 3 barriers ago: safe
        COMPUTE(b0);
        char* tmp = b0; b0 = b1; b1 = b2; b2 = b3; b3 = tmp;
    }
    WAITV(14); __builtin_amdgcn_s_barrier(); COMPUTE(b0);   // tile NT-3
    WAITV(7);  __builtin_amdgcn_s_barrier(); COMPUTE(b1);   // tile NT-2
    WAITV(0);  __builtin_amdgcn_s_barrier(); COMPUTE(b2);   // tile NT-1

    // epilogue: pred - isum (bf16 precomputed), accumulate squared error
    float local = 0.f;
    #pragma unroll
    for (int m = 0; m < 4; ++m){
        int rbase = m0 + wr*64 + m*16 + g*4;
        #pragma unroll
        for (int n = 0; n < 3; ++n){
            int col = n0 + wc*48 + n*16 + s;
            #pragma unroll
            for (int jj = 0; jj < 4; ++jj){
                float is = bf2f(isum[(size_t)(rbase+jj)*OUT_F + col]);
                float d = accv[m][n][jj] - is;
                local += d*d;
            }
        }
    }
    #pragma unroll
    for (int off = 32; off; off >>= 1) local += __shfl_down(local, off);
    if (l == 0) part[w] = local;
    __syncthreads();
    if (tid == 0){
        atomicAdd(&acc[0], part[0]+part[1]+part[2]+part[3]);
    }
}

// ---------------- kernel 4: finalize ----------------------------------------
__global__ void finalize(const float* __restrict__ acc, float* __restrict__ out){
    out[0] = acc[0] * (1.0f / ((float)BATCH * (float)OUT_F * 128.0f));
    out[1] = acc[1] * (1.0f / ((float)IN_F * (float)WCOLS));
}

extern "C" void kernel_launch(void* const* d_in, const int* in_sizes, int n_in,
                              void* d_out, int out_size, void* d_ws, size_t ws_size,
                              hipStream_t stream){
    const float* latent   = (const float*)d_in[0];
    const float* true_sum = (const float*)d_in[1];
    const float* weight   = (const float*)d_in[2];
    float* acc = (float*)d_ws;
    unsigned short* abf  = (unsigned short*)((char*)d_ws + 1024);
    unsigned short* bt   = (unsigned short*)((char*)d_ws + 1024 + (size_t)BATCH*IN_F*2);
    unsigned short* isum = (unsigned short*)((char*)d_ws + 1024 + (size_t)BATCH*IN_F*2
                                             + (size_t)OUT_F*IN_F*2);
    float* out = (float*)d_out;

    prep_latent<<<(BATCH*IN_F)/(256*8), 256, 0, stream>>>(latent, abf, acc);
    decode_weight<<<dim3(IN_F/64, OUT_F/64), 256, 0, stream>>>(weight, bt, acc);
    ts_decode<<<(BATCH*OUT_F)/(256*6), 256, 0, stream>>>(true_sum, isum);
    gemm_loss<<<dim3(BATCH/BM, OUT_F/BN), 256, 0, stream>>>(abf, bt, isum, acc);
    finalize<<<1, 1, 0, stream>>>(acc, out);
}

// Round 4
// 105.534 us; speedup vs baseline: 1.2612x; 1.2612x over previous
//
#include <hip/hip_runtime.h>
#include <stdint.h>

#define IN_F   4096
#define OUT_F  768
#define NB     8
#define BATCH  4096
#define WCOLS  (OUT_F*NB)   // 6144

typedef short  bf16x8  __attribute__((ext_vector_type(8)));
typedef float  f32x4   __attribute__((ext_vector_type(4)));
typedef unsigned short ushort8 __attribute__((ext_vector_type(8)));

__device__ __forceinline__ unsigned short f2bf(float f){
    union { float f; uint32_t u; } v; v.f = f;
    uint32_t u = v.u;
    u += 0x7FFFu + ((u >> 16) & 1u);   // round-to-nearest-even
    return (unsigned short)(u >> 16);
}

__device__ __forceinline__ float bf2f(unsigned short u){
    union { uint32_t q; float f; } v; v.q = ((uint32_t)u) << 16;
    return v.f;
}

__device__ __forceinline__ void gload16(const void* g, void* l){
    __builtin_amdgcn_global_load_lds(
        (const __attribute__((address_space(1))) unsigned int*)g,
        (__attribute__((address_space(3))) unsigned int*)l, 16, 0, 0);
}

// counted vmcnt wait + scheduler fence (rule #18)
#define WAITV(n) do {                                                   \
    asm volatile("s_waitcnt vmcnt(" #n ")" ::: "memory");               \
    __builtin_amdgcn_sched_barrier(0);                                  \
} while (0)

// ---------------- kernel 1: latent f32 -> bf16 ; zero accumulators ----------
__global__ void prep_latent(const float* __restrict__ lat,
                            unsigned short* __restrict__ abf,
                            float* __restrict__ acc){
    if (blockIdx.x == 0 && threadIdx.x < 4) acc[threadIdx.x] = 0.f;
    int idx = (blockIdx.x * 256 + threadIdx.x) * 8;   // 8 floats / thread
    const float4* p = (const float4*)(lat + idx);
    float4 a = p[0], b = p[1];
    ushort8 o;
    o[0]=f2bf(a.x); o[1]=f2bf(a.y); o[2]=f2bf(a.z); o[3]=f2bf(a.w);
    o[4]=f2bf(b.x); o[5]=f2bf(b.y); o[6]=f2bf(b.z); o[7]=f2bf(b.w);
    *(ushort8*)(abf + idx) = o;
}

// ---------------- kernel 2: sigmoid-decode weight -> int_weights^T (bf16) ---
__global__ void decode_weight(const float* __restrict__ w,
                              unsigned short* __restrict__ bt,
                              float* __restrict__ acc){
    __shared__ unsigned short tile[64][70];   // [n][k], padded stride
    __shared__ float part[4];
    const int tid = threadIdx.x;
    const int k0 = blockIdx.x * 64;
    const int n0 = blockIdx.y * 64;
    const int j     = tid & 63;        // n within tile
    const int ibase = (tid >> 6) * 16; // k within tile
    float pol = 0.f;
    #pragma unroll 4
    for (int r = 0; r < 16; ++r){
        int i = ibase + r;
        const float4* src = (const float4*)(w + (size_t)(k0+i)*WCOLS + (size_t)(n0+j)*8);
        float4 a = src[0], b = src[1];
        float x[8] = {a.x,a.y,a.z,a.w,b.x,b.y,b.z,b.w};
        float p[8];
        #pragma unroll
        for (int q = 0; q < 8; ++q){
            p[q] = 1.f / (1.f + __expf(-x[q]));
            pol += p[q] * (1.f - p[q]);
        }
        float iw = p[0] + 2.f*p[1] + 4.f*p[2] + 8.f*p[3]
                 + 16.f*p[4] + 32.f*p[5] + 64.f*p[6] - 128.f*p[7];
        tile[j][i] = f2bf(iw);
    }
    #pragma unroll
    for (int off = 32; off; off >>= 1) pol += __shfl_down(pol, off);
    if ((tid & 63) == 0) part[tid >> 6] = pol;
    __syncthreads();
    const int nrow = tid >> 4;
    const int kb   = (tid & 15) * 4;
    #pragma unroll
    for (int q = 0; q < 4; ++q){
        int n = nrow + q*16;
        uint2 v;
        v.x = *(const unsigned int*)&tile[n][kb];
        v.y = *(const unsigned int*)&tile[n][kb+2];
        *(uint2*)(bt + (size_t)(n0+n)*IN_F + k0 + kb) = v;
    }
    if (tid == 0) atomicAdd(&acc[1], part[0]+part[1]+part[2]+part[3]);
}

// ---------------- kernel 2b: true_sum bits -> isum (bf16, [BATCH][OUT_F]) ---
__global__ void ts_decode(const float* __restrict__ ts,
                          unsigned short* __restrict__ isum){
    const int tid = threadIdx.x;
    #pragma unroll
    for (int k = 0; k < 6; ++k){
        int e = blockIdx.x * 1536 + k * 256 + tid;
        const float4* q = (const float4*)(ts + (size_t)e * 8);
        float4 x = q[0], y = q[1];
        float v = x.x + 2.f*x.y + 4.f*x.z + 8.f*x.w
                + 16.f*y.x + 32.f*y.y + 64.f*y.z - 128.f*y.w;
        isum[e] = f2bf(v);
    }
}

// ---------------- kernel 3: bf16 GEMM, 2 blocks/CU, depth-2 pipeline --------
#define BM 64
#define BN 96
#define BK 64
#define NT (IN_F/BK)            // 64 K-steps
#define ABYTES (BM*BK*2)        // 8192
#define BBYTES (BN*BK*2)        // 12288
#define BUFB   (ABYTES+BBYTES)  // 20480

__launch_bounds__(256, 2)
__global__ void gemm_loss(const unsigned short* __restrict__ abf,
                          const unsigned short* __restrict__ bt,
                          const unsigned short* __restrict__ isum,
                          float* __restrict__ acc){
    __shared__ char smem[3*BUFB];   // 60 KB -> 2 blocks/CU
    __shared__ float part[4];
    const int tid = threadIdx.x;
    const int w   = tid >> 6;
    const int l   = tid & 63;
    const int s   = l & 15, g = l >> 4;
    const int wr  = w >> 1, wc = w & 1;    // 2x2 waves, wave tile 32x48
    const int m0  = blockIdx.x * BM;
    const int n0  = blockIdx.y * BN;

    f32x4 accv[2][3];
    #pragma unroll
    for (int m = 0; m < 2; ++m)
        #pragma unroll
        for (int n = 0; n < 3; ++n)
            accv[m][n] = (f32x4){0.f,0.f,0.f,0.f};

    // staging: thread t covers LDS row t>>3 (+32 strides), chunk col t&7
    // (linear LDS dest); source chunk XOR-swizzled to match swizzled ds_reads
    const int c8  = tid & 7;
    const int r0  = tid >> 3;                    // 0..31; (r0+32i)&7 == r0&7
    const int scw = ((c8 ^ (r0 & 7)) << 3);      // source element offset
    const unsigned short* aS = abf + (size_t)(m0 + r0) * IN_F + scw;
    const unsigned short* bS = bt  + (size_t)(n0 + r0) * IN_F + scw;

    // 5 uniform loads / wave / stage  (A: 2, B: 3)
    #define STAGE(kt, base) do {                                           \
        const int _ko = (kt) * BK;                                         \
        char* _ad = (base) + tid*16;                                       \
        char* _bd = (base) + ABYTES + tid*16;                              \
        gload16(aS + _ko,                      _ad);                       \
        gload16(aS + (size_t)32*IN_F + _ko,    _ad + 4096);                \
        gload16(bS + _ko,                      _bd);                       \
        gload16(bS + (size_t)32*IN_F + _ko,    _bd + 4096);                \
        gload16(bS + (size_t)64*IN_F + _ko,    _bd + 8192);                \
    } while (0)

    #define COMPUTE(base) do {                                             \
        char* _Ab = (base);                                                \
        char* _Bb = (base) + ABYTES;                                       \
        _Pragma("unroll")                                                  \
        for (int _kk = 0; _kk < 2; ++_kk){                                 \
            bf16x8 _af[2], _bf[3];                                         \
            _Pragma("unroll")                                              \
            for (int _m = 0; _m < 2; ++_m){                                \
                int _r  = wr*32 + _m*16 + s;                               \
                int _ch = _r*8 + ((_kk*4 + g) ^ (_r & 7));                 \
                _af[_m] = *(const bf16x8*)(_Ab + _ch*16);                  \
            }                                                              \
            _Pragma("unroll")                                              \
            for (int _n = 0; _n < 3; ++_n){                                \
                int _r  = wc*48 + _n*16 + s;                               \
                int _ch = _r*8 + ((_kk*4 + g) ^ (_r & 7));                 \
                _bf[_n] = *(const bf16x8*)(_Bb + _ch*16);                  \
            }                                                              \
            _Pragma("unroll")                                              \
            for (int _m = 0; _m < 2; ++_m)                                 \
                _Pragma("unroll")                                          \
                for (int _n = 0; _n < 3; ++_n)                             \
                    accv[_m][_n] = __builtin_amdgcn_mfma_f32_16x16x32_bf16(\
                        _af[_m], _bf[_n], accv[_m][_n], 0, 0, 0);          \
        }                                                                  \
    } while (0)

    char* p0 = smem;             // tile t   (compute)
    char* p1 = smem + BUFB;      // tile t+1 (in flight)
    char* p2 = smem + 2*BUFB;    // tile t+2 (stage target; freed at t-1)

    // depth-2 prefetch; <=10 loads/wave in flight; ONE barrier per K-step;
    // vmcnt never drained inside the loop.
    STAGE(0, p0);
    STAGE(1, p1);
    for (int t = 0; t < NT-1; ++t){
        WAITV(5);                          // this wave's tile-t loads landed
        __builtin_amdgcn_s_barrier();      // tile t visible; p2 free (all
                                           // waves passed COMPUTE(t-1))
        if (t + 2 < NT) STAGE(t + 2, p2);  // issue early: covered by compute
        COMPUTE(p0);
        char* tmp = p0; p0 = p1; p1 = p2; p2 = tmp;
    }
    WAITV(0);
    __builtin_amdgcn_s_barrier();
    COMPUTE(p0);                           // tile NT-1

    // epilogue: pred - isum (bf16 precomputed), accumulate squared error
    float local = 0.f;
    #pragma unroll
    for (int m = 0; m < 2; ++m){
        int rbase = m0 + wr*32 + m*16 + g*4;
        #pragma unroll
        for (int n = 0; n < 3; ++n){
            int col = n0 + wc*48 + n*16 + s;
            #pragma unroll
            for (int jj = 0; jj < 4; ++jj){
                float is = bf2f(isum[(size_t)(rbase+jj)*OUT_F + col]);
                float d = accv[m][n][jj] - is;
                local += d*d;
            }
        }
    }
    #pragma unroll
    for (int off = 32; off; off >>= 1) local += __shfl_down(local, off);
    if (l == 0) part[w] = local;
    __syncthreads();
    if (tid == 0){
        atomicAdd(&acc[0], part[0]+part[1]+part[2]+part[3]);
    }
}

// ---------------- kernel 4: finalize ----------------------------------------
__global__ void finalize(const float* __restrict__ acc, float* __restrict__ out){
    out[0] = acc[0] * (1.0f / ((float)BATCH * (float)OUT_F * 128.0f));
    out[1] = acc[1] * (1.0f / ((float)IN_F * (float)WCOLS));
}

extern "C" void kernel_launch(void* const* d_in, const int* in_sizes, int n_in,
                              void* d_out, int out_size, void* d_ws, size_t ws_size,
                              hipStream_t stream){
    const float* latent   = (const float*)d_in[0];
    const float* true_sum = (const float*)d_in[1];
    const float* weight   = (const float*)d_in[2];
    float* acc = (float*)d_ws;
    unsigned short* abf  = (unsigned short*)((char*)d_ws + 1024);
    unsigned short* bt   = (unsigned short*)((char*)d_ws + 1024 + (size_t)BATCH*IN_F*2);
    unsigned short* isum = (unsigned short*)((char*)d_ws + 1024 + (size_t)BATCH*IN_F*2
                                             + (size_t)OUT_F*IN_F*2);
    float* out = (float*)d_out;

    prep_latent<<<(BATCH*IN_F)/(256*8), 256, 0, stream>>>(latent, abf, acc);
    decode_weight<<<dim3(IN_F/64, OUT_F/64), 256, 0, stream>>>(weight, bt, acc);
    ts_decode<<<(BATCH*OUT_F)/(256*6), 256, 0, stream>>>(true_sum, isum);
    gemm_loss<<<dim3(BATCH/BM, OUT_F/BN), 256, 0, stream>>>(abf, bt, isum, acc);
    finalize<<<1, 1, 0, stream>>>(acc, out);
}